// Round 5
// baseline (140.136 us; speedup 1.0000x reference)
//
#include <hip/hip_runtime.h>
#include <stdint.h>

#define VOCAB 21128
#define NUMC  53
#define EMB   128
#define SEQ   512
#define BATCH 512

typedef __bf16 bf16x8 __attribute__((ext_vector_type(8)));
typedef float f32x4 __attribute__((ext_vector_type(4)));

__device__ __forceinline__ unsigned int f2bf1(float f) {
    union { float f; unsigned int u; } v; v.f = f;
    return (v.u + 0x7FFFu + ((v.u >> 16) & 1u)) >> 16;
}
__device__ __forceinline__ unsigned int pack2(float a, float b) {
    return f2bf1(a) | (f2bf1(b) << 16);
}

// Prep (tiny): conv_w -> Wp bf16 in per-lane B-fragment order:
// Wp[s 0..11][g 0..7][lane 0..63][j 0..7] = w[f=g*16+(lane&15)][e=kk&127][tap=kk>>7],
// kk = s*32 + (lane>>4)*8 + j
__global__ void prep_w(const float* __restrict__ cw, unsigned short* __restrict__ Wp) {
    int idx = blockIdx.x * blockDim.x + threadIdx.x;
    if (idx < 12 * 8 * 64 * 8) {
        int j = idx & 7, l = (idx >> 3) & 63, g = (idx >> 9) & 7, s = idx >> 12;
        int kk = s * 32 + (l >> 4) * 8 + j;
        int f = g * 16 + (l & 15);
        int tap = kk >> 7, e = kk & 127;
        Wp[idx] = (unsigned short)f2bf1(cw[(f * EMB + e) * 3 + tap]);
    }
}

// 4096 blocks: block (b, tq) = batch row b, positions [tq*64, tq*64+64).
// 128 threads = 2 waves; wave wn covers filters [wn*64, wn*64+64) via 4 n-steps.
// Stage: gather fp32 emb rows directly (row 0 is zeros = padding_idx), convert
// to bf16 into LDS (66 halo'd rows x 128 emb, row stride 136 hw). One cheap
// 2-wave barrier; MFMA 16x16x32 bf16; piecewise max partials straight to Pd.
__launch_bounds__(128)
__global__ void pcnn_tile(const int* __restrict__ cid, const int* __restrict__ p1,
                          const int* __restrict__ p2, const float* __restrict__ emb,
                          const unsigned short* __restrict__ Wp,
                          float* __restrict__ Pd) {
    __shared__ __align__(16) unsigned short xs[66 * 136];  // 17,952 B

    const int bx   = blockIdx.x;
    const int b    = bx >> 3;
    const int tq   = bx & 7;
    const int tid  = threadIdx.x;
    const int lane = tid & 63;
    const int wn   = tid >> 6;
    const int quad = lane >> 4;
    const int lc   = lane & 15;

    // ---- Stage: 66 rows x 16 chunks (32 B fp32 in -> 16 B bf16 out) = 1056 tasks
#pragma unroll
    for (int i = 0; i < 9; ++i) {
        int task = tid + 128 * i;
        if (task < 1056) {
            int r = task >> 4, c = task & 15;
            int p = tq * 64 + r - 1;
            int id = (p >= 0 && p < SEQ) ? cid[(size_t)b * SEQ + p] : 0;  // emb row 0 = zeros
            const float4* src = (const float4*)(emb + (size_t)id * EMB + c * 8);
            float4 a = src[0], d = src[1];
            uint4 o;
            o.x = pack2(a.x, a.y);
            o.y = pack2(a.z, a.w);
            o.z = pack2(d.x, d.y);
            o.w = pack2(d.z, d.w);
            *(uint4*)(&xs[r * 136 + c * 8]) = o;
        }
    }

    int e1 = min(p1[b], p2[b]);
    int e2 = max(p1[b], p2[b]);
    if (e1 == e2) e2 = min(e1 + 1, SEQ);
    const int e1m = max(e1, 1);

    __syncthreads();  // 2-wave barrier

    // ---- Conv: M=64 (4 mt), N=64/wave (4 nt), K=384 (12 s)
    f32x4 acc[4][4];
#pragma unroll
    for (int mt = 0; mt < 4; ++mt)
#pragma unroll
        for (int nt = 0; nt < 4; ++nt)
            acc[mt][nt] = (f32x4){0.f, 0.f, 0.f, 0.f};

#pragma unroll
    for (int s = 0; s < 12; ++s) {
        const int tap = s >> 2;
        const int eb  = (s & 3) * 32;
        bf16x8 af[4];
#pragma unroll
        for (int mt = 0; mt < 4; ++mt) {
            int r = mt * 16 + lc + tap;  // output pos tq*64+m needs input pos m+tap-1 -> row m+tap
            af[mt] = *(const bf16x8*)(xs + r * 136 + eb + quad * 8);
        }
#pragma unroll
        for (int nt = 0; nt < 4; ++nt) {
            int g = wn * 4 + nt;
            bf16x8 bf = *(const bf16x8*)(Wp + (size_t)((s * 8 + g) * 64 + lane) * 8);
#pragma unroll
            for (int mt = 0; mt < 4; ++mt)
                acc[mt][nt] = __builtin_amdgcn_mfma_f32_16x16x32_bf16(af[mt], bf, acc[mt][nt], 0, 0, 0);
        }
    }

    // ---- Piecewise max over this block's 64 positions (raw conv; bias+relu in combine)
    float smax[3][4];
#pragma unroll
    for (int s3 = 0; s3 < 3; ++s3)
#pragma unroll
        for (int nt = 0; nt < 4; ++nt) smax[s3][nt] = -1e30f;

#pragma unroll
    for (int mt = 0; mt < 4; ++mt)
#pragma unroll
        for (int reg = 0; reg < 4; ++reg) {
            int p = tq * 64 + mt * 16 + quad * 4 + reg;
            float a0 = (p < e1m) ? 0.f : -2e30f;
            float a1 = (p >= e1 && p < e2) ? 0.f : -2e30f;
            float a2 = (p >= e2) ? 0.f : -2e30f;
#pragma unroll
            for (int nt = 0; nt < 4; ++nt) {
                float v = acc[mt][nt][reg];
                smax[0][nt] = fmaxf(smax[0][nt], v + a0);
                smax[1][nt] = fmaxf(smax[1][nt], v + a1);
                smax[2][nt] = fmaxf(smax[2][nt], v + a2);
            }
        }

    // Reduce over quads (lanes ^16, ^32); lanes 0..15 write straight to Pd
#pragma unroll
    for (int s3 = 0; s3 < 3; ++s3)
#pragma unroll
        for (int nt = 0; nt < 4; ++nt) {
            float v = smax[s3][nt];
            v = fmaxf(v, __shfl_xor(v, 16));
            v = fmaxf(v, __shfl_xor(v, 32));
            smax[s3][nt] = v;
        }
    if (lane < 16) {
        size_t base = ((size_t)(b * 8 + tq) * 3) * 128;
#pragma unroll
        for (int s3 = 0; s3 < 3; ++s3)
#pragma unroll
            for (int nt = 0; nt < 4; ++nt)
                Pd[base + (size_t)s3 * 128 + wn * 64 + nt * 16 + lc] = smax[s3][nt];
    }
}

// Combine: max over 8 tile-partials, bias+ReLU, FC 384->53. One block per row.
__launch_bounds__(256, 4)
__global__ void pcnn_combine(const float* __restrict__ Pd, const float* __restrict__ cb,
                             const float* __restrict__ fcw, const float* __restrict__ fcb,
                             float* __restrict__ out) {
    __shared__ float pooled[384];
    __shared__ float fcred[NUMC][4];
    const int b = blockIdx.x;
    const int tid = threadIdx.x;

    for (int j = tid; j < 384; j += 256) {
        int s3 = j >> 7, f = j & 127;
        const float* pp = Pd + ((size_t)b * 8 * 3 + s3) * 128 + f;
        float m = -1e30f;
#pragma unroll
        for (int tq = 0; tq < 8; ++tq) m = fmaxf(m, pp[(size_t)tq * 384]);
        pooled[j] = fmaxf(m + cb[f], 0.f);
    }
    __syncthreads();

    if (tid < 212) {
        int c = tid >> 2, q = tid & 3;
        const float* wrow = fcw + (size_t)c * 384 + q * 96;
        const float* pp   = pooled + q * 96;
        float sum = 0.f;
#pragma unroll 8
        for (int i = 0; i < 96; ++i) sum += wrow[i] * pp[i];
        fcred[c][q] = sum;
    }
    __syncthreads();
    if (tid < NUMC)
        out[(size_t)b * NUMC + tid] =
            fcred[tid][0] + fcred[tid][1] + fcred[tid][2] + fcred[tid][3] + fcb[tid];
}

extern "C" void kernel_launch(void* const* d_in, const int* in_sizes, int n_in,
                              void* d_out, int out_size, void* d_ws, size_t ws_size,
                              hipStream_t stream) {
    const int*   cid = (const int*)d_in[0];
    const int*   p1  = (const int*)d_in[1];
    const int*   p2  = (const int*)d_in[2];
    const float* emb = (const float*)d_in[3];
    const float* cw  = (const float*)d_in[4];
    const float* cb  = (const float*)d_in[5];
    const float* fcw = (const float*)d_in[6];
    const float* fcb = (const float*)d_in[7];
    float* out = (float*)d_out;

    // ws: Wp bf16 [49152] (98,304 B) | Pd fp32 [512*8*3*128] (6,291,456 B)
    unsigned short* Wp = (unsigned short*)d_ws;
    float*          Pd = (float*)((char*)d_ws + 98304);

    prep_w<<<96, 512, 0, stream>>>(cw, Wp);
    pcnn_tile<<<BATCH * 8, 128, 0, stream>>>(cid, p1, p2, emb, Wp, Pd);
    pcnn_combine<<<BATCH, 256, 0, stream>>>(Pd, cb, fcw, fcb, out);
}